// Round 1
// baseline (859.047 us; speedup 1.0000x reference)
//
#include <hip/hip_runtime.h>
#include <hip/hip_bf16.h>

#define H 1024
#define B 32
#define S 2048

typedef __attribute__((ext_vector_type(8))) short bf16x8;
typedef __attribute__((ext_vector_type(4))) float f32x4;

union U4 { uint4 u; bf16x8 b; };

__device__ __forceinline__ unsigned short f2bf(float f) {
    unsigned u = __float_as_uint(f);
    unsigned r = (u + 0x7fffu + ((u >> 16) & 1u)) >> 16;
    return (unsigned short)r;
}

__device__ __forceinline__ float ftanh(float x) {
    // tanh(x) = 1 - 2/(e^{2x}+1); clamp 2x to +-30 (tanh saturated to ~1e-13)
    float x2 = __builtin_amdgcn_fmed3f(x + x, -30.f, 30.f);
    float e = __expf(x2);
    return 1.f - 2.f * __builtin_amdgcn_rcpf(e + 1.f);
}

// ---------------------------------------------------------------------------
// K0: convert Ua_w (fp32 [n][k] row-major, n=out,k=h) to bf16 in MFMA B-frag
// swizzled order: ws layout [kc(32)][nt(64)][lane(64)][j(8)]
//   n = nt*16 + (lane&15); k = kc*32 + (lane>>4)*8 + j
__global__ void k0_swizzle(const float* __restrict__ Ua, unsigned short* __restrict__ UaSw) {
    int t = blockIdx.x * 256 + threadIdx.x;   // 0..131071
    int lane = t & 63;
    int nt = (t >> 6) & 63;
    int kc = t >> 12;
    int n = nt * 16 + (lane & 15);
    int k = kc * 32 + ((lane >> 4) & 3) * 8;
    const float4* src = (const float4*)(Ua + (size_t)n * H + k);
    float4 x = src[0], y = src[1];
    uint4 p;
    p.x = (unsigned)f2bf(x.x) | ((unsigned)f2bf(x.y) << 16);
    p.y = (unsigned)f2bf(x.z) | ((unsigned)f2bf(x.w) << 16);
    p.z = (unsigned)f2bf(y.x) | ((unsigned)f2bf(y.y) << 16);
    p.w = (unsigned)f2bf(y.z) | ((unsigned)f2bf(y.w) << 16);
    ((uint4*)UaSw)[t] = p;
}

// ---------------------------------------------------------------------------
// K1: qp[b][n] = sum_h query[b][h]*Wa_w[n][h] + Wa_b[n] + Ua_b[n]
__global__ void k1_qproj(const float* __restrict__ q, const float* __restrict__ Wa,
                         const float* __restrict__ Wab, const float* __restrict__ Uab,
                         float* __restrict__ qp) {
    int b = blockIdx.y;
    int n = blockIdx.x * 256 + threadIdx.x;
    __shared__ float qs[H];
    for (int i = threadIdx.x; i < H; i += 256) qs[i] = q[b * H + i];
    __syncthreads();
    float acc = 0.f;
    const float4* wr = (const float4*)(Wa + (size_t)n * H);
#pragma unroll 4
    for (int h4 = 0; h4 < H / 4; h4++) {
        float4 w = wr[h4];
        acc += qs[h4 * 4 + 0] * w.x + qs[h4 * 4 + 1] * w.y +
               qs[h4 * 4 + 2] * w.z + qs[h4 * 4 + 3] * w.w;
    }
    qp[b * H + n] = acc + Wab[n] + Uab[n];
}

// ---------------------------------------------------------------------------
// K2: scores[b][s] = sum_n tanh(qp[b][n] + keys[b,s,:].Ua[n,:]) * Va[n]  (+Va_b added here)
// 512 threads = 8 waves = 2 s-waves x 4 n-waves. s-tile 64, full N=1024.
// Wave (sw,nw): rows s0+sw*32+[0,32), n-tiles nt_global = nw + 4*j, j=0..15.
// kc loop over K in steps of 32; B staged in 2 phases of 32 n-tiles (32 KB).
__global__ __launch_bounds__(512, 2) void k2_scores(
    const float* __restrict__ keys, const unsigned short* __restrict__ UaSw,
    const float* __restrict__ qp, const float* __restrict__ Vaw,
    const float* __restrict__ Vab, float* __restrict__ scores) {
    __shared__ uint4 As[256];        // [sw(2)][mt(2)][lane(64)] : 4 KB
    __shared__ uint4 Bs[2048];       // [nt_local(32)][lane(64)] : 32 KB
    __shared__ float Ps[4][2][32];   // [nw][sw][row]

    const int tid = threadIdx.x;
    const int lane = tid & 63;
    const int wave = tid >> 6;
    const int sw = wave >> 2;        // 0..1
    const int nw = wave & 3;         // 0..3
    const int s0 = blockIdx.x * 64;
    const int b = blockIdx.y;

    f32x4 acc[2][16];
#pragma unroll
    for (int mt = 0; mt < 2; mt++)
#pragma unroll
        for (int j = 0; j < 16; j++) acc[mt][j] = (f32x4){0.f, 0.f, 0.f, 0.f};

    const float4* keys4 = (const float4*)keys;
    const uint4* UaSw4 = (const uint4*)UaSw;

    for (int kc = 0; kc < 32; kc++) {
        __syncthreads();  // protect As/Bs from previous iteration reads
        // ---- stage A: keys[b, s0..s0+63, kc*32..+32) -> bf16 frag order
        if (tid < 256) {
            int lg = tid & 63, mt = (tid >> 6) & 1, swg = (tid >> 7) & 1;
            int s = s0 + swg * 32 + mt * 16 + (lg & 15);
            int k = kc * 32 + (lg >> 4) * 8;
            const float4* src = keys4 + ((size_t)(b * S + s) * (H / 4) + (k >> 2));
            float4 x = src[0], y = src[1];
            uint4 p;
            p.x = (unsigned)f2bf(x.x) | ((unsigned)f2bf(x.y) << 16);
            p.y = (unsigned)f2bf(x.z) | ((unsigned)f2bf(x.w) << 16);
            p.z = (unsigned)f2bf(y.x) | ((unsigned)f2bf(y.y) << 16);
            p.w = (unsigned)f2bf(y.z) | ((unsigned)f2bf(y.w) << 16);
            As[tid] = p;
        }
        // ---- stage B phase 0: nt_global 0..31
        {
            const uint4* srcB = UaSw4 + (size_t)kc * 4096;
#pragma unroll
            for (int i = 0; i < 4; i++) Bs[tid + i * 512] = srcB[tid + i * 512];
        }
        __syncthreads();
        U4 a0, a1;
        a0.u = As[(sw * 2 + 0) * 64 + lane];
        a1.u = As[(sw * 2 + 1) * 64 + lane];
#pragma unroll
        for (int j = 0; j < 8; j++) {
            int ntl = nw + j * 4;  // nt_global in [0,32)
            U4 bf; bf.u = Bs[ntl * 64 + lane];
            acc[0][j] = __builtin_amdgcn_mfma_f32_16x16x32_bf16(a0.b, bf.b, acc[0][j], 0, 0, 0);
            acc[1][j] = __builtin_amdgcn_mfma_f32_16x16x32_bf16(a1.b, bf.b, acc[1][j], 0, 0, 0);
        }
        __syncthreads();  // phase-0 Bs reads done
        // ---- stage B phase 1: nt_global 32..63
        {
            const uint4* srcB = UaSw4 + (size_t)kc * 4096 + 2048;
#pragma unroll
            for (int i = 0; i < 4; i++) Bs[tid + i * 512] = srcB[tid + i * 512];
        }
        __syncthreads();
#pragma unroll
        for (int j = 8; j < 16; j++) {
            int ntl = nw + j * 4 - 32;  // local slot
            U4 bf; bf.u = Bs[ntl * 64 + lane];
            acc[0][j] = __builtin_amdgcn_mfma_f32_16x16x32_bf16(a0.b, bf.b, acc[0][j], 0, 0, 0);
            acc[1][j] = __builtin_amdgcn_mfma_f32_16x16x32_bf16(a1.b, bf.b, acc[1][j], 0, 0, 0);
        }
    }

    // ---- epilogue: tanh, dot with Va, reduce over n
    const int col = lane & 15, q = lane >> 4;
    float rs[2][4] = {{0.f, 0.f, 0.f, 0.f}, {0.f, 0.f, 0.f, 0.f}};
#pragma unroll
    for (int j = 0; j < 16; j++) {
        int n = (nw + j * 4) * 16 + col;
        float qv = qp[b * H + n];
        float vv = Vaw[n];
#pragma unroll
        for (int mt = 0; mt < 2; mt++)
#pragma unroll
            for (int r = 0; r < 4; r++) {
                float t = ftanh(acc[mt][j][r] + qv);
                rs[mt][r] += t * vv;
            }
    }
#pragma unroll
    for (int mt = 0; mt < 2; mt++)
#pragma unroll
        for (int r = 0; r < 4; r++) {
            float v = rs[mt][r];
            v += __shfl_xor(v, 1, 64);
            v += __shfl_xor(v, 2, 64);
            v += __shfl_xor(v, 4, 64);
            v += __shfl_xor(v, 8, 64);
            rs[mt][r] = v;
        }
    if (col == 0) {
#pragma unroll
        for (int mt = 0; mt < 2; mt++)
#pragma unroll
            for (int r = 0; r < 4; r++) Ps[nw][sw][mt * 16 + q * 4 + r] = rs[mt][r];
    }
    __syncthreads();
    if (tid < 64) {
        int sw2 = tid >> 5, row = tid & 31;
        float sum = Ps[0][sw2][row] + Ps[1][sw2][row] + Ps[2][sw2][row] + Ps[3][sw2][row] + Vab[0];
        scores[b * S + s0 + sw2 * 32 + row] = sum;
    }
}

// ---------------------------------------------------------------------------
// K3: softmax over S per b -> weights written to out[32768 + b*S + s]
__global__ void k3_softmax(const float* __restrict__ scores, float* __restrict__ out) {
    int b = blockIdx.x, t = threadIdx.x;
    __shared__ float red[256];
    float v[8];
    float lm = -1e30f;
#pragma unroll
    for (int i = 0; i < 8; i++) {
        v[i] = scores[b * S + i * 256 + t];
        lm = fmaxf(lm, v[i]);
    }
    red[t] = lm;
    __syncthreads();
    for (int s = 128; s > 0; s >>= 1) {
        if (t < s) red[t] = fmaxf(red[t], red[t + s]);
        __syncthreads();
    }
    float m = red[0];
    __syncthreads();
    float ls = 0.f;
#pragma unroll
    for (int i = 0; i < 8; i++) {
        v[i] = __expf(v[i] - m);
        ls += v[i];
    }
    red[t] = ls;
    __syncthreads();
    for (int s = 128; s > 0; s >>= 1) {
        if (t < s) red[t] += red[t + s];
        __syncthreads();
    }
    float inv = 1.f / red[0];
#pragma unroll
    for (int i = 0; i < 8; i++) out[B * H + b * S + i * 256 + t] = v[i] * inv;
}

// ---------------------------------------------------------------------------
// K4: context[b][h] += sum_{s in chunk} w[b][s]*keys[b][s][h]  (atomics, ctx pre-zeroed)
__global__ void k4_ctx(const float* __restrict__ keys, const float* __restrict__ out_w,
                       float* __restrict__ out_c) {
    int sc = blockIdx.x, hc = blockIdx.y, b = blockIdx.z;
    int t = threadIdx.x;
    __shared__ float wl[256];
    wl[t] = out_w[B * H + b * S + sc * 256 + t];
    __syncthreads();
    int h = hc * 256 + t;
    const float* kp = keys + (size_t)(b * S + sc * 256) * H + h;
    float acc = 0.f;
#pragma unroll 4
    for (int i = 0; i < 256; i++) acc += wl[i] * kp[(size_t)i * H];
    atomicAdd(out_c + b * H + h, acc);
}

// ---------------------------------------------------------------------------
extern "C" void kernel_launch(void* const* d_in, const int* in_sizes, int n_in,
                              void* d_out, int out_size, void* d_ws, size_t ws_size,
                              hipStream_t stream) {
    const float* query = (const float*)d_in[0];
    const float* keys  = (const float*)d_in[1];
    const float* Wa_w  = (const float*)d_in[2];
    const float* Wa_b  = (const float*)d_in[3];
    const float* Ua_w  = (const float*)d_in[4];
    const float* Ua_b  = (const float*)d_in[5];
    const float* Va_w  = (const float*)d_in[6];
    const float* Va_b  = (const float*)d_in[7];
    float* out = (float*)d_out;

    // workspace: [0,2MB) UaSw bf16 swizzled; [2MB,+128KB) qp; then scores 256KB
    unsigned short* UaSw = (unsigned short*)d_ws;
    float* qp = (float*)((char*)d_ws + (2u << 20));
    float* scores = (float*)((char*)d_ws + (2u << 20) + (128u << 10));

    // zero context region of out (re-poisoned to 0xAA before every launch)
    hipMemsetAsync(d_out, 0, B * H * sizeof(float), stream);

    k0_swizzle<<<512, 256, 0, stream>>>(Ua_w, UaSw);
    k1_qproj<<<dim3(4, B), 256, 0, stream>>>(query, Wa_w, Wa_b, Ua_b, qp);
    k2_scores<<<dim3(S / 64, B), 512, 0, stream>>>(keys, UaSw, qp, Va_w, Va_b, scores);
    k3_softmax<<<B, 256, 0, stream>>>(scores, out);
    k4_ctx<<<dim3(S / 256, H / 256, B), 256, 0, stream>>>(keys, out, out);
}

// Round 2
// 668.267 us; speedup vs baseline: 1.2855x; 1.2855x over previous
//
#include <hip/hip_runtime.h>
#include <hip/hip_bf16.h>

#define H 1024
#define B 32
#define S 2048

typedef __attribute__((ext_vector_type(8))) short bf16x8;
typedef __attribute__((ext_vector_type(4))) float f32x4;

union U4 { uint4 u; bf16x8 b; };

__device__ __forceinline__ unsigned short f2bf(float f) {
    unsigned u = __float_as_uint(f);
    unsigned r = (u + 0x7fffu + ((u >> 16) & 1u)) >> 16;
    return (unsigned short)r;
}

__device__ __forceinline__ uint4 pack8(float4 x, float4 y) {
    uint4 p;
    p.x = (unsigned)f2bf(x.x) | ((unsigned)f2bf(x.y) << 16);
    p.y = (unsigned)f2bf(x.z) | ((unsigned)f2bf(x.w) << 16);
    p.z = (unsigned)f2bf(y.x) | ((unsigned)f2bf(y.y) << 16);
    p.w = (unsigned)f2bf(y.z) | ((unsigned)f2bf(y.w) << 16);
    return p;
}

__device__ __forceinline__ float ftanh(float x) {
    float x2 = __builtin_amdgcn_fmed3f(x + x, -30.f, 30.f);
    float e = __expf(x2);
    return 1.f - 2.f * __builtin_amdgcn_rcpf(e + 1.f);
}

__device__ __forceinline__ void async_copy16(const void* g, void* l) {
    __builtin_amdgcn_global_load_lds(
        (const __attribute__((address_space(1))) unsigned int*)g,
        (__attribute__((address_space(3))) unsigned int*)l, 16, 0, 0);
}

// ---------------------------------------------------------------------------
// K0: Ua_w fp32 [n][k] -> bf16 MFMA-B-frag order: UaSw[nb(8)][kc(32)][ent(512)]
// ent = nt*64 + lane; n = nb*128 + nt*16 + (lane&15); k = kc*32 + ((lane>>4)&3)*8 + j
__global__ void k0_swizzle(const float* __restrict__ Ua, uint4* __restrict__ UaSw) {
    int t = blockIdx.x * 256 + threadIdx.x;   // 0..131071
    int lane = t & 63;
    int nt = (t >> 6) & 7;
    int kc = (t >> 9) & 31;
    int nb = t >> 14;
    int n = nb * 128 + nt * 16 + (lane & 15);
    int k = kc * 32 + ((lane >> 4) & 3) * 8;
    const float4* src = (const float4*)(Ua + (size_t)n * H + k);
    UaSw[t] = pack8(src[0], src[1]);
}

// ---------------------------------------------------------------------------
// K1: qp[b][n] = sum_h query[b][h]*Wa_w[n][h] + Wa_b[n] + Ua_b[n]
__global__ void k1_qproj(const float* __restrict__ q, const float* __restrict__ Wa,
                         const float* __restrict__ Wab, const float* __restrict__ Uab,
                         float* __restrict__ qp) {
    int b = blockIdx.y;
    int n = blockIdx.x * 256 + threadIdx.x;
    __shared__ float qs[H];
    for (int i = threadIdx.x; i < H; i += 256) qs[i] = q[b * H + i];
    __syncthreads();
    float acc = 0.f;
    const float4* wr = (const float4*)(Wa + (size_t)n * H);
#pragma unroll 4
    for (int h4 = 0; h4 < H / 4; h4++) {
        float4 w = wr[h4];
        acc += qs[h4 * 4 + 0] * w.x + qs[h4 * 4 + 1] * w.y +
               qs[h4 * 4 + 2] * w.z + qs[h4 * 4 + 3] * w.w;
    }
    qp[b * H + n] = acc + Wab[n] + Uab[n];
}

// ---------------------------------------------------------------------------
// K2: m97-style 128x128 GEMM tile, BK=32, 4 waves (2x2), partial-N with
// atomicAdd score reduction. scores[b][s] += sum_{n in nb} tanh(kp+qp)*Va[n]
__global__ __launch_bounds__(256, 3) void k2_scores(
    const float* __restrict__ keys, const uint4* __restrict__ UaSw,
    const float* __restrict__ qp, const float* __restrict__ Vaw,
    float* __restrict__ scores) {
    __shared__ uint4 As[512];        // [mt(8)][lane(64)] : 8 KB
    __shared__ uint4 Bs[512];        // [nt(8)][lane(64)] : 8 KB
    __shared__ float part[2][128];

    const int tid = threadIdx.x;
    const int lane = tid & 63;
    const int wave = tid >> 6;
    const int wm = wave >> 1, wn = wave & 1;
    const int nb = blockIdx.x;       // 0..7
    const int mb = blockIdx.y;       // 0..511
    const int b = mb >> 4;
    const int s0 = (mb & 15) << 7;

    // A staging: thread covers ent = tid (mt 0..3) and tid+256 (mt 4..7)
    const int el = tid & 63;
    const int srow0 = s0 + (tid >> 6) * 16 + (el & 15);
    const int srow1 = srow0 + 64;
    const int kofs = ((el >> 4) & 3) * 8;
    const float4* ka0 = (const float4*)(keys + ((size_t)b * S + srow0) * H + kofs);
    const float4* ka1 = (const float4*)(keys + ((size_t)b * S + srow1) * H + kofs);
    const uint4* srcB = UaSw + (size_t)nb * 32 * 512;

    f32x4 acc[4][4];
#pragma unroll
    for (int mt = 0; mt < 4; mt++)
#pragma unroll
        for (int nt = 0; nt < 4; nt++) acc[mt][nt] = (f32x4){0.f, 0.f, 0.f, 0.f};

    // prologue: prefetch A fp32 for kc=0
    float4 x0 = ka0[0], y0 = ka0[1], x1 = ka1[0], y1 = ka1[1];

    for (int kc = 0; kc < 32; kc++) {
        __syncthreads();   // previous iteration's frag reads done
        // B tile: async global->LDS, 8 KB
        async_copy16(srcB + (size_t)kc * 512 + tid,       &Bs[tid]);
        async_copy16(srcB + (size_t)kc * 512 + tid + 256, &Bs[tid + 256]);
        // A tile: pack prefetched fp32 -> bf16 frags
        As[tid]       = pack8(x0, y0);
        As[tid + 256] = pack8(x1, y1);
        if (kc < 31) {   // prefetch next kc
            x0 = ka0[(kc + 1) * 8]; y0 = ka0[(kc + 1) * 8 + 1];
            x1 = ka1[(kc + 1) * 8]; y1 = ka1[(kc + 1) * 8 + 1];
        }
        __syncthreads();   // drains global_load_lds (vmcnt) + ds_writes
        U4 af[4], bf[4];
#pragma unroll
        for (int mt = 0; mt < 4; mt++) af[mt].u = As[(wm * 4 + mt) * 64 + lane];
#pragma unroll
        for (int nt = 0; nt < 4; nt++) bf[nt].u = Bs[(wn * 4 + nt) * 64 + lane];
#pragma unroll
        for (int mt = 0; mt < 4; mt++)
#pragma unroll
            for (int nt = 0; nt < 4; nt++)
                acc[mt][nt] = __builtin_amdgcn_mfma_f32_16x16x32_bf16(
                    af[mt].b, bf[nt].b, acc[mt][nt], 0, 0, 0);
    }

    // epilogue: tanh, dot Va, reduce over this block's 128 n
    const int col = lane & 15, q = lane >> 4;
    float qv[4], vv[4];
#pragma unroll
    for (int nt = 0; nt < 4; nt++) {
        int n = nb * 128 + (wn * 4 + nt) * 16 + col;
        qv[nt] = qp[b * H + n];
        vv[nt] = Vaw[n];
    }
#pragma unroll
    for (int mt = 0; mt < 4; mt++) {
        float rs[4] = {0.f, 0.f, 0.f, 0.f};
#pragma unroll
        for (int nt = 0; nt < 4; nt++)
#pragma unroll
            for (int r = 0; r < 4; r++)
                rs[r] += ftanh(acc[mt][nt][r] + qv[nt]) * vv[nt];
#pragma unroll
        for (int r = 0; r < 4; r++) {
            float v = rs[r];
            v += __shfl_xor(v, 1, 64);
            v += __shfl_xor(v, 2, 64);
            v += __shfl_xor(v, 4, 64);
            v += __shfl_xor(v, 8, 64);
            if (col == 0) part[wn][wm * 64 + mt * 16 + q * 4 + r] = v;
        }
    }
    __syncthreads();
    if (tid < 128)
        atomicAdd(&scores[b * S + s0 + tid], part[0][tid] + part[1][tid]);
}

// ---------------------------------------------------------------------------
// K3: softmax over S per b -> weights at out[B*H + b*S + s]
__global__ void k3_softmax(const float* __restrict__ scores, float* __restrict__ out) {
    int b = blockIdx.x, t = threadIdx.x;
    __shared__ float red[256];
    float v[8];
    float lm = -1e30f;
#pragma unroll
    for (int i = 0; i < 8; i++) {
        v[i] = scores[b * S + i * 256 + t];
        lm = fmaxf(lm, v[i]);
    }
    red[t] = lm;
    __syncthreads();
    for (int s = 128; s > 0; s >>= 1) {
        if (t < s) red[t] = fmaxf(red[t], red[t + s]);
        __syncthreads();
    }
    float m = red[0];
    __syncthreads();
    float ls = 0.f;
#pragma unroll
    for (int i = 0; i < 8; i++) {
        v[i] = __expf(v[i] - m);
        ls += v[i];
    }
    red[t] = ls;
    __syncthreads();
    for (int s = 128; s > 0; s >>= 1) {
        if (t < s) red[t] += red[t + s];
        __syncthreads();
    }
    float inv = 1.f / red[0];
#pragma unroll
    for (int i = 0; i < 8; i++) out[B * H + b * S + i * 256 + t] = v[i] * inv;
}

// ---------------------------------------------------------------------------
// K4: context[b][h] += sum_{s in chunk} w[b][s]*keys[b][s][h]
// one block per (s-chunk, b): 256 threads cover full H as float4
__global__ __launch_bounds__(256) void k4_ctx(const float* __restrict__ keys,
                                              const float* __restrict__ out_w,
                                              float* __restrict__ out_c) {
    int sc = blockIdx.x, b = blockIdx.y;
    int t = threadIdx.x;
    __shared__ float wl[256];
    wl[t] = out_w[B * H + b * S + sc * 256 + t];
    __syncthreads();
    const float4* kp = (const float4*)(keys + ((size_t)b * S + sc * 256) * H) + t;
    float4 acc = {0.f, 0.f, 0.f, 0.f};
#pragma unroll 8
    for (int s = 0; s < 256; s++) {
        float4 kv = kp[(size_t)s * 256];
        float w = wl[s];
        acc.x += w * kv.x; acc.y += w * kv.y;
        acc.z += w * kv.z; acc.w += w * kv.w;
    }
    float* dst = out_c + b * H + t * 4;
    atomicAdd(dst + 0, acc.x);
    atomicAdd(dst + 1, acc.y);
    atomicAdd(dst + 2, acc.z);
    atomicAdd(dst + 3, acc.w);
}

// ---------------------------------------------------------------------------
extern "C" void kernel_launch(void* const* d_in, const int* in_sizes, int n_in,
                              void* d_out, int out_size, void* d_ws, size_t ws_size,
                              hipStream_t stream) {
    const float* query = (const float*)d_in[0];
    const float* keys  = (const float*)d_in[1];
    const float* Wa_w  = (const float*)d_in[2];
    const float* Wa_b  = (const float*)d_in[3];
    const float* Ua_w  = (const float*)d_in[4];
    const float* Ua_b  = (const float*)d_in[5];
    const float* Va_w  = (const float*)d_in[6];
    float* out = (float*)d_out;

    // ws: [0,2MB) UaSw bf16 swizzled; [2MB,+128KB) qp; [+128KB,+384KB) scores
    uint4* UaSw = (uint4*)d_ws;
    float* qp = (float*)((char*)d_ws + (2u << 20));
    float* scores = (float*)((char*)d_ws + (2u << 20) + (128u << 10));

    hipMemsetAsync(d_out, 0, B * H * sizeof(float), stream);      // context acc
    hipMemsetAsync(scores, 0, B * S * sizeof(float), stream);     // score acc

    k0_swizzle<<<512, 256, 0, stream>>>(Ua_w, UaSw);
    k1_qproj<<<dim3(4, B), 256, 0, stream>>>(query, Wa_w, Wa_b, Ua_b, qp);
    k2_scores<<<dim3(8, 512), 256, 0, stream>>>(keys, UaSw, qp, Va_w, scores);
    k3_softmax<<<B, 256, 0, stream>>>(scores, out);
    k4_ctx<<<dim3(S / 256, B), 256, 0, stream>>>(keys, out, out);
}

// Round 3
// 658.228 us; speedup vs baseline: 1.3051x; 1.0153x over previous
//
#include <hip/hip_runtime.h>
#include <hip/hip_bf16.h>

#define H 1024
#define B 32
#define S 2048

typedef __attribute__((ext_vector_type(8))) short bf16x8;
typedef __attribute__((ext_vector_type(4))) float f32x4;

union U4 { uint4 u; bf16x8 b; };

__device__ __forceinline__ unsigned short f2bf(float f) {
    unsigned u = __float_as_uint(f);
    unsigned r = (u + 0x7fffu + ((u >> 16) & 1u)) >> 16;
    return (unsigned short)r;
}

__device__ __forceinline__ uint4 pack8(float4 x, float4 y) {
    uint4 p;
    p.x = (unsigned)f2bf(x.x) | ((unsigned)f2bf(x.y) << 16);
    p.y = (unsigned)f2bf(x.z) | ((unsigned)f2bf(x.w) << 16);
    p.z = (unsigned)f2bf(y.x) | ((unsigned)f2bf(y.y) << 16);
    p.w = (unsigned)f2bf(y.z) | ((unsigned)f2bf(y.w) << 16);
    return p;
}

__device__ __forceinline__ float ftanh(float x) {
    float x2 = __builtin_amdgcn_fmed3f(x + x, -30.f, 30.f);
    float e = __expf(x2);
    return 1.f - 2.f * __builtin_amdgcn_rcpf(e + 1.f);
}

__device__ __forceinline__ void async_copy16(const void* g, void* l) {
    __builtin_amdgcn_global_load_lds(
        (const __attribute__((address_space(1))) unsigned int*)g,
        (__attribute__((address_space(3))) unsigned int*)l, 16, 0, 0);
}

// ---------------------------------------------------------------------------
// K0: Ua_w fp32 [n][k] -> bf16 MFMA-B-frag order: UaSw[nb(8)][kc(32)][ent(512)]
__global__ void k0_swizzle(const float* __restrict__ Ua, uint4* __restrict__ UaSw) {
    int t = blockIdx.x * 256 + threadIdx.x;   // 0..131071
    int lane = t & 63;
    int nt = (t >> 6) & 7;
    int kc = (t >> 9) & 31;
    int nb = t >> 14;
    int n = nb * 128 + nt * 16 + (lane & 15);
    int k = kc * 32 + ((lane >> 4) & 3) * 8;
    const float4* src = (const float4*)(Ua + (size_t)n * H + k);
    UaSw[t] = pack8(src[0], src[1]);
}

// ---------------------------------------------------------------------------
// K1: qp[b][n] = sum_h query[b][h]*Wa_w[n][h] + Wa_b[n] + Ua_b[n]
__global__ void k1_qproj(const float* __restrict__ q, const float* __restrict__ Wa,
                         const float* __restrict__ Wab, const float* __restrict__ Uab,
                         float* __restrict__ qp) {
    int b = blockIdx.y;
    int n = blockIdx.x * 256 + threadIdx.x;
    __shared__ float qs[H];
    for (int i = threadIdx.x; i < H; i += 256) qs[i] = q[b * H + i];
    __syncthreads();
    float acc = 0.f;
    const float4* wr = (const float4*)(Wa + (size_t)n * H);
#pragma unroll 4
    for (int h4 = 0; h4 < H / 4; h4++) {
        float4 w = wr[h4];
        acc += qs[h4 * 4 + 0] * w.x + qs[h4 * 4 + 1] * w.y +
               qs[h4 * 4 + 2] * w.z + qs[h4 * 4 + 3] * w.w;
    }
    qp[b * H + n] = acc + Wab[n] + Uab[n];
}

// ---------------------------------------------------------------------------
// K2: 128x128 GEMM tile, BK=32, 4 waves (2x2), partial-N, atomicAdd scores.
// XCD-aware decode: the 8 nb-blocks sharing an A-tile are adjacent in one
// XCD's dispatch queue (round-robin by linear id assumed) -> A-slice L2 reuse.
__global__ __launch_bounds__(256, 3) void k2_scores(
    const float* __restrict__ keys, const uint4* __restrict__ UaSw,
    const float* __restrict__ qp, const float* __restrict__ Vaw,
    float* __restrict__ scores) {
    __shared__ uint4 As[512];        // 8 KB
    __shared__ uint4 Bs[512];        // 8 KB
    __shared__ float part[2][128];

    const int tid = threadIdx.x;
    const int lane = tid & 63;
    const int wave = tid >> 6;
    const int wm = wave >> 1, wn = wave & 1;
    const int lid = blockIdx.x;      // 0..4095
    const int c = lid & 7;           // XCD slot
    const int qq = lid >> 3;
    const int nb = qq & 7;           // n-block 0..7, cycles fastest per-XCD
    const int mb = (qq >> 3) * 8 + c; // 0..511
    const int b = mb >> 4;
    const int s0 = (mb & 15) << 7;

    const int el = tid & 63;
    const int srow0 = s0 + (tid >> 6) * 16 + (el & 15);
    const int srow1 = srow0 + 64;
    const int kofs = ((el >> 4) & 3) * 8;
    const float4* ka0 = (const float4*)(keys + ((size_t)b * S + srow0) * H + kofs);
    const float4* ka1 = (const float4*)(keys + ((size_t)b * S + srow1) * H + kofs);
    const uint4* srcB = UaSw + (size_t)nb * 32 * 512;

    f32x4 acc[4][4];
#pragma unroll
    for (int mt = 0; mt < 4; mt++)
#pragma unroll
        for (int nt = 0; nt < 4; nt++) acc[mt][nt] = (f32x4){0.f, 0.f, 0.f, 0.f};

    float4 x0 = ka0[0], y0 = ka0[1], x1 = ka1[0], y1 = ka1[1];

    for (int kc = 0; kc < 32; kc++) {
        __syncthreads();
        async_copy16(srcB + (size_t)kc * 512 + tid,       &Bs[tid]);
        async_copy16(srcB + (size_t)kc * 512 + tid + 256, &Bs[tid + 256]);
        As[tid]       = pack8(x0, y0);
        As[tid + 256] = pack8(x1, y1);
        if (kc < 31) {
            x0 = ka0[(kc + 1) * 8]; y0 = ka0[(kc + 1) * 8 + 1];
            x1 = ka1[(kc + 1) * 8]; y1 = ka1[(kc + 1) * 8 + 1];
        }
        __syncthreads();
        U4 af[4], bf[4];
#pragma unroll
        for (int mt = 0; mt < 4; mt++) af[mt].u = As[(wm * 4 + mt) * 64 + lane];
#pragma unroll
        for (int nt = 0; nt < 4; nt++) bf[nt].u = Bs[(wn * 4 + nt) * 64 + lane];
#pragma unroll
        for (int mt = 0; mt < 4; mt++)
#pragma unroll
            for (int nt = 0; nt < 4; nt++)
                acc[mt][nt] = __builtin_amdgcn_mfma_f32_16x16x32_bf16(
                    af[mt].b, bf[nt].b, acc[mt][nt], 0, 0, 0);
    }

    const int col = lane & 15, qd = lane >> 4;
    float qv[4], vv[4];
#pragma unroll
    for (int nt = 0; nt < 4; nt++) {
        int n = nb * 128 + (wn * 4 + nt) * 16 + col;
        qv[nt] = qp[b * H + n];
        vv[nt] = Vaw[n];
    }
#pragma unroll
    for (int mt = 0; mt < 4; mt++) {
        float rs[4] = {0.f, 0.f, 0.f, 0.f};
#pragma unroll
        for (int nt = 0; nt < 4; nt++)
#pragma unroll
            for (int r = 0; r < 4; r++)
                rs[r] += ftanh(acc[mt][nt][r] + qv[nt]) * vv[nt];
#pragma unroll
        for (int r = 0; r < 4; r++) {
            float v = rs[r];
            v += __shfl_xor(v, 1, 64);
            v += __shfl_xor(v, 2, 64);
            v += __shfl_xor(v, 4, 64);
            v += __shfl_xor(v, 8, 64);
            if (col == 0) part[wn][wm * 64 + mt * 16 + qd * 4 + r] = v;
        }
    }
    __syncthreads();
    if (tid < 128)
        atomicAdd(&scores[b * S + s0 + tid], part[0][tid] + part[1][tid]);
}

// ---------------------------------------------------------------------------
// K4: fused softmax + weights-write + context partial.
// grid (16,32): block (sc,b) recomputes softmax stats for row b (redundant,
// cheap), writes weights slice [sc*128, sc*128+128), accumulates context.
__global__ __launch_bounds__(256) void k4_ctx(const float* __restrict__ keys,
                                              const float* __restrict__ scores,
                                              float* __restrict__ out) {
    int sc = blockIdx.x, b = blockIdx.y;
    int t = threadIdx.x;
    __shared__ float red[256];
    __shared__ float wl[128];

    // softmax stats over full row b (each thread: 8 strided elements)
    float v[8];
    float lm = -1e30f;
#pragma unroll
    for (int i = 0; i < 8; i++) {
        v[i] = scores[b * S + i * 256 + t];
        lm = fmaxf(lm, v[i]);
    }
    red[t] = lm;
    __syncthreads();
    for (int s = 128; s > 0; s >>= 1) {
        if (t < s) red[t] = fmaxf(red[t], red[t + s]);
        __syncthreads();
    }
    float m = red[0];
    __syncthreads();
    float ls = 0.f;
#pragma unroll
    for (int i = 0; i < 8; i++) ls += __expf(v[i] - m);
    red[t] = ls;
    __syncthreads();
    for (int s = 128; s > 0; s >>= 1) {
        if (t < s) red[t] += red[t + s];
        __syncthreads();
    }
    float inv = 1.f / red[0];

    // weights slice: write once (this block owns [sc*128, sc*128+128))
    if (t < 128) {
        float w = __expf(scores[b * S + sc * 128 + t] - m) * inv;
        wl[t] = w;
        out[B * H + b * S + sc * 128 + t] = w;
    }
    __syncthreads();

    // context partial over 128 rows
    const float4* kp = (const float4*)(keys + ((size_t)b * S + sc * 128) * H) + t;
    float4 acc = {0.f, 0.f, 0.f, 0.f};
#pragma unroll 8
    for (int s = 0; s < 128; s++) {
        float4 kv = kp[(size_t)s * 256];
        float w = wl[s];
        acc.x += w * kv.x; acc.y += w * kv.y;
        acc.z += w * kv.z; acc.w += w * kv.w;
    }
    float* dst = out + b * H + t * 4;
    atomicAdd(dst + 0, acc.x);
    atomicAdd(dst + 1, acc.y);
    atomicAdd(dst + 2, acc.z);
    atomicAdd(dst + 3, acc.w);
}

// ---------------------------------------------------------------------------
extern "C" void kernel_launch(void* const* d_in, const int* in_sizes, int n_in,
                              void* d_out, int out_size, void* d_ws, size_t ws_size,
                              hipStream_t stream) {
    const float* query = (const float*)d_in[0];
    const float* keys  = (const float*)d_in[1];
    const float* Wa_w  = (const float*)d_in[2];
    const float* Wa_b  = (const float*)d_in[3];
    const float* Ua_w  = (const float*)d_in[4];
    const float* Ua_b  = (const float*)d_in[5];
    const float* Va_w  = (const float*)d_in[6];
    float* out = (float*)d_out;

    // ws: [0,2MB) UaSw bf16 swizzled; [2MB,+128KB) qp; [+128KB,+384KB) scores
    uint4* UaSw = (uint4*)d_ws;
    float* qp = (float*)((char*)d_ws + (2u << 20));
    float* scores = (float*)((char*)d_ws + (2u << 20) + (128u << 10));

    hipMemsetAsync(d_out, 0, B * H * sizeof(float), stream);      // context acc
    hipMemsetAsync(scores, 0, B * S * sizeof(float), stream);     // score acc

    k0_swizzle<<<512, 256, 0, stream>>>(Ua_w, UaSw);
    k1_qproj<<<dim3(4, B), 256, 0, stream>>>(query, Wa_w, Wa_b, Ua_b, qp);
    k2_scores<<<4096, 256, 0, stream>>>(keys, UaSw, qp, Va_w, scores);
    k4_ctx<<<dim3(16, B), 256, 0, stream>>>(keys, scores, out);
}

// Round 4
// 649.967 us; speedup vs baseline: 1.3217x; 1.0127x over previous
//
#include <hip/hip_runtime.h>
#include <hip/hip_bf16.h>

#define H 1024
#define B 32
#define S 2048

typedef __attribute__((ext_vector_type(8))) short bf16x8;
typedef __attribute__((ext_vector_type(4))) float f32x4;

union U4 { uint4 u; bf16x8 b; };

__device__ __forceinline__ unsigned short f2bf(float f) {
    unsigned u = __float_as_uint(f);
    unsigned r = (u + 0x7fffu + ((u >> 16) & 1u)) >> 16;
    return (unsigned short)r;
}

__device__ __forceinline__ uint4 pack8(float4 x, float4 y) {
    uint4 p;
    p.x = (unsigned)f2bf(x.x) | ((unsigned)f2bf(x.y) << 16);
    p.y = (unsigned)f2bf(x.z) | ((unsigned)f2bf(x.w) << 16);
    p.z = (unsigned)f2bf(y.x) | ((unsigned)f2bf(y.y) << 16);
    p.w = (unsigned)f2bf(y.z) | ((unsigned)f2bf(y.w) << 16);
    return p;
}

__device__ __forceinline__ float ftanh(float x) {
    float x2 = __builtin_amdgcn_fmed3f(x + x, -30.f, 30.f);
    float e = __expf(x2);
    return 1.f - 2.f * __builtin_amdgcn_rcpf(e + 1.f);
}

__device__ __forceinline__ void async_copy16(const void* g, void* l) {
    __builtin_amdgcn_global_load_lds(
        (const __attribute__((address_space(1))) unsigned int*)g,
        (__attribute__((address_space(3))) unsigned int*)l, 16, 0, 0);
}

// ---------------------------------------------------------------------------
// K0: Ua_w fp32 [n][k] -> bf16 MFMA-B-frag order: UaSw[nb(8)][kc(32)][ent(512)]
__global__ void k0_swizzle(const float* __restrict__ Ua, uint4* __restrict__ UaSw) {
    int t = blockIdx.x * 256 + threadIdx.x;   // 0..131071
    int lane = t & 63;
    int nt = (t >> 6) & 7;
    int kc = (t >> 9) & 31;
    int nb = t >> 14;
    int n = nb * 128 + nt * 16 + (lane & 15);
    int k = kc * 32 + ((lane >> 4) & 3) * 8;
    const float4* src = (const float4*)(Ua + (size_t)n * H + k);
    UaSw[t] = pack8(src[0], src[1]);
}

// ---------------------------------------------------------------------------
// K1: qp[b][n] = sum_h query[b][h]*Wa_w[n][h] + Wa_b[n] + Ua_b[n]
// 4 threads per row (coalesced 64B segments), shfl-combine quarters.
__global__ __launch_bounds__(256) void k1_qproj(
    const float* __restrict__ q, const float* __restrict__ Wa,
    const float* __restrict__ Wab, const float* __restrict__ Uab,
    float* __restrict__ qp) {
    int b = blockIdx.y;
    int t = threadIdx.x;
    int n = blockIdx.x * 64 + (t >> 2);
    int quarter = t & 3;
    __shared__ float qs[H];
    for (int i = t; i < H; i += 256) qs[i] = q[b * H + i];
    __syncthreads();
    const float4* wr = (const float4*)(Wa + (size_t)n * H + quarter * 256);
    const float* qq = qs + quarter * 256;
    float acc = 0.f;
#pragma unroll 4
    for (int i = 0; i < 64; i++) {
        float4 w = wr[i];
        acc += qq[i * 4 + 0] * w.x + qq[i * 4 + 1] * w.y +
               qq[i * 4 + 2] * w.z + qq[i * 4 + 3] * w.w;
    }
    acc += __shfl_xor(acc, 1, 64);
    acc += __shfl_xor(acc, 2, 64);
    if (quarter == 0) qp[b * H + n] = acc + Wab[n] + Uab[n];
}

// ---------------------------------------------------------------------------
// K2: 128x128 GEMM tile, BK=32, double-buffered LDS, 1 barrier per kc.
// Staging (async B->LDS[nxt], pack A->LDS[nxt], A-regs prefetch kc+2) issued
// BEFORE the MFMA phase on LDS[cur] so the barrier's vmcnt drain is covered.
// Per-nb score partials written non-atomically to sp[nb][b][s].
__global__ __launch_bounds__(256, 3) void k2_scores(
    const float* __restrict__ keys, const uint4* __restrict__ UaSw,
    const float* __restrict__ qp, const float* __restrict__ Vaw,
    float* __restrict__ sp) {
    __shared__ uint4 As[2][512];     // 16 KB
    __shared__ uint4 Bs[2][512];     // 16 KB
    __shared__ float part[2][128];

    const int tid = threadIdx.x;
    const int lane = tid & 63;
    const int wave = tid >> 6;
    const int wm = wave >> 1, wn = wave & 1;
    const int lid = blockIdx.x;      // 0..4095
    const int c = lid & 7;           // XCD slot (round-robin by linear id)
    const int qq = lid >> 3;
    const int nb = qq & 7;           // nb cycles fastest within an XCD
    const int mb = (qq >> 3) * 8 + c;
    const int b = mb >> 4;
    const int s0 = (mb & 15) << 7;

    const int el = tid & 63;
    const int srow0 = s0 + (tid >> 6) * 16 + (el & 15);
    const int srow1 = srow0 + 64;
    const int kofs = ((el >> 4) & 3) * 8;
    const float4* ka0 = (const float4*)(keys + ((size_t)b * S + srow0) * H + kofs);
    const float4* ka1 = (const float4*)(keys + ((size_t)b * S + srow1) * H + kofs);
    const uint4* srcB = UaSw + (size_t)nb * 32 * 512;

    f32x4 acc[4][4];
#pragma unroll
    for (int mt = 0; mt < 4; mt++)
#pragma unroll
        for (int nt = 0; nt < 4; nt++) acc[mt][nt] = (f32x4){0.f, 0.f, 0.f, 0.f};

    // prologue: stage kc=0 into buffer 0; prefetch A-regs for kc=1
    float4 x0 = ka0[0], y0 = ka0[1], x1 = ka1[0], y1 = ka1[1];
    async_copy16(srcB + tid,       &Bs[0][tid]);
    async_copy16(srcB + tid + 256, &Bs[0][tid + 256]);
    As[0][tid]       = pack8(x0, y0);
    As[0][tid + 256] = pack8(x1, y1);
    x0 = ka0[8]; y0 = ka0[9]; x1 = ka1[8]; y1 = ka1[9];
    __syncthreads();

    for (int kc = 0; kc < 32; kc++) {
        const int cur = kc & 1, nxt = cur ^ 1;
        if (kc < 31) {
            // stage kc+1 into nxt BEFORE compute on cur
            async_copy16(srcB + (size_t)(kc + 1) * 512 + tid,       &Bs[nxt][tid]);
            async_copy16(srcB + (size_t)(kc + 1) * 512 + tid + 256, &Bs[nxt][tid + 256]);
            As[nxt][tid]       = pack8(x0, y0);
            As[nxt][tid + 256] = pack8(x1, y1);
            if (kc < 30) {
                x0 = ka0[(kc + 2) * 8]; y0 = ka0[(kc + 2) * 8 + 1];
                x1 = ka1[(kc + 2) * 8]; y1 = ka1[(kc + 2) * 8 + 1];
            }
        }
        U4 af[4], bf[4];
#pragma unroll
        for (int mt = 0; mt < 4; mt++) af[mt].u = As[cur][(wm * 4 + mt) * 64 + lane];
#pragma unroll
        for (int nt = 0; nt < 4; nt++) bf[nt].u = Bs[cur][(wn * 4 + nt) * 64 + lane];
#pragma unroll
        for (int mt = 0; mt < 4; mt++)
#pragma unroll
            for (int nt = 0; nt < 4; nt++)
                acc[mt][nt] = __builtin_amdgcn_mfma_f32_16x16x32_bf16(
                    af[mt].b, bf[nt].b, acc[mt][nt], 0, 0, 0);
        __syncthreads();
    }

    // epilogue: tanh, dot Va, reduce over this block's 128 n
    const int col = lane & 15, qd = lane >> 4;
    float qv[4], vv[4];
#pragma unroll
    for (int nt = 0; nt < 4; nt++) {
        int n = nb * 128 + (wn * 4 + nt) * 16 + col;
        qv[nt] = qp[b * H + n];
        vv[nt] = Vaw[n];
    }
#pragma unroll
    for (int mt = 0; mt < 4; mt++) {
        float rs[4] = {0.f, 0.f, 0.f, 0.f};
#pragma unroll
        for (int nt = 0; nt < 4; nt++)
#pragma unroll
            for (int r = 0; r < 4; r++)
                rs[r] += ftanh(acc[mt][nt][r] + qv[nt]) * vv[nt];
#pragma unroll
        for (int r = 0; r < 4; r++) {
            float v = rs[r];
            v += __shfl_xor(v, 1, 64);
            v += __shfl_xor(v, 2, 64);
            v += __shfl_xor(v, 4, 64);
            v += __shfl_xor(v, 8, 64);
            if (col == 0) part[wn][wm * 64 + mt * 16 + qd * 4 + r] = v;
        }
    }
    __syncthreads();
    if (tid < 128)
        sp[(size_t)nb * B * S + b * S + s0 + tid] = part[0][tid] + part[1][tid];
}

// ---------------------------------------------------------------------------
// K4: fused partial-sum + softmax + weights-write + context partial.
// grid (32,32): block (sc,b) owns 64 s-rows. Stats recomputed per block
// (L2-hot 64KB of sp). Context partials accumulated via atomics.
__global__ __launch_bounds__(256) void k4_ctx(const float* __restrict__ keys,
                                              const float* __restrict__ sp,
                                              float* __restrict__ out) {
    int sc = blockIdx.x, b = blockIdx.y;
    int t = threadIdx.x;
    __shared__ float red[256];
    __shared__ float wl[64];

    // scores row b = sum of 8 nb-partials; each thread handles 8 strided s
    float v[8];
#pragma unroll
    for (int i = 0; i < 8; i++) {
        int s = i * 256 + t;
        float sum = 0.f;
#pragma unroll
        for (int nb = 0; nb < 8; nb++) sum += sp[(size_t)nb * B * S + b * S + s];
        v[i] = sum;
    }
    float lm = -1e30f;
#pragma unroll
    for (int i = 0; i < 8; i++) lm = fmaxf(lm, v[i]);
    red[t] = lm;
    __syncthreads();
    for (int s = 128; s > 0; s >>= 1) {
        if (t < s) red[t] = fmaxf(red[t], red[t + s]);
        __syncthreads();
    }
    float m = red[0];
    __syncthreads();
    float ls = 0.f;
#pragma unroll
    for (int i = 0; i < 8; i++) ls += __expf(v[i] - m);
    red[t] = ls;
    __syncthreads();
    for (int s = 128; s > 0; s >>= 1) {
        if (t < s) red[t] += red[t + s];
        __syncthreads();
    }
    float inv = 1.f / red[0];

    // weights slice [sc*64, sc*64+64)
    if (t < 64) {
        int s = sc * 64 + t;
        float sum = 0.f;
#pragma unroll
        for (int nb = 0; nb < 8; nb++) sum += sp[(size_t)nb * B * S + b * S + s];
        float w = __expf(sum - m) * inv;
        wl[t] = w;
        out[B * H + b * S + s] = w;
    }
    __syncthreads();

    // context partial over 64 rows
    const float4* kp = (const float4*)(keys + ((size_t)b * S + sc * 64) * H) + t;
    float4 acc = {0.f, 0.f, 0.f, 0.f};
#pragma unroll 8
    for (int s = 0; s < 64; s++) {
        float4 kv = kp[(size_t)s * 256];
        float w = wl[s];
        acc.x += w * kv.x; acc.y += w * kv.y;
        acc.z += w * kv.z; acc.w += w * kv.w;
    }
    float* dst = out + b * H + t * 4;
    atomicAdd(dst + 0, acc.x);
    atomicAdd(dst + 1, acc.y);
    atomicAdd(dst + 2, acc.z);
    atomicAdd(dst + 3, acc.w);
}

// ---------------------------------------------------------------------------
extern "C" void kernel_launch(void* const* d_in, const int* in_sizes, int n_in,
                              void* d_out, int out_size, void* d_ws, size_t ws_size,
                              hipStream_t stream) {
    const float* query = (const float*)d_in[0];
    const float* keys  = (const float*)d_in[1];
    const float* Wa_w  = (const float*)d_in[2];
    const float* Wa_b  = (const float*)d_in[3];
    const float* Ua_w  = (const float*)d_in[4];
    const float* Ua_b  = (const float*)d_in[5];
    const float* Va_w  = (const float*)d_in[6];
    float* out = (float*)d_out;

    // ws: [0,2MB) UaSw; [2MB,+128KB) qp; [2MB+128KB, +2MB) sp[8][B][S]
    uint4* UaSw = (uint4*)d_ws;
    float* qp = (float*)((char*)d_ws + (2u << 20));
    float* sp = (float*)((char*)d_ws + (2u << 20) + (128u << 10));

    hipMemsetAsync(d_out, 0, B * H * sizeof(float), stream);  // context acc

    k0_swizzle<<<512, 256, 0, stream>>>(Ua_w, UaSw);
    k1_qproj<<<dim3(16, B), 256, 0, stream>>>(query, Wa_w, Wa_b, Ua_b, qp);
    k2_scores<<<4096, 256, 0, stream>>>(keys, UaSw, qp, Va_w, sp);
    k4_ctx<<<dim3(32, B), 256, 0, stream>>>(keys, sp, out);
}

// Round 5
// 592.076 us; speedup vs baseline: 1.4509x; 1.0978x over previous
//
#include <hip/hip_runtime.h>
#include <hip/hip_bf16.h>

#define H 1024
#define B 32
#define S 2048

typedef __attribute__((ext_vector_type(8))) short bf16x8;
typedef __attribute__((ext_vector_type(4))) float f32x4;

union U4 { uint4 u; bf16x8 b; };

__device__ __forceinline__ unsigned short f2bf(float f) {
    unsigned u = __float_as_uint(f);
    unsigned r = (u + 0x7fffu + ((u >> 16) & 1u)) >> 16;
    return (unsigned short)r;
}

__device__ __forceinline__ uint4 pack8(float4 x, float4 y) {
    uint4 p;
    p.x = (unsigned)f2bf(x.x) | ((unsigned)f2bf(x.y) << 16);
    p.y = (unsigned)f2bf(x.z) | ((unsigned)f2bf(x.w) << 16);
    p.z = (unsigned)f2bf(y.x) | ((unsigned)f2bf(y.y) << 16);
    p.w = (unsigned)f2bf(y.z) | ((unsigned)f2bf(y.w) << 16);
    return p;
}

__device__ __forceinline__ float ftanh(float x) {
    float x2 = __builtin_amdgcn_fmed3f(x + x, -30.f, 30.f);
    float e = __expf(x2);
    return 1.f - 2.f * __builtin_amdgcn_rcpf(e + 1.f);
}

__device__ __forceinline__ void async_copy16(const void* g, void* l) {
    __builtin_amdgcn_global_load_lds(
        (const __attribute__((address_space(1))) unsigned int*)g,
        (__attribute__((address_space(3))) unsigned int*)l, 16, 0, 0);
}

// ---------------------------------------------------------------------------
// K0: Ua_w fp32 [n][k] -> bf16 MFMA-B-frag order: UaSw[nb(8)][kc(32)][nt(8)*64+lane]
__global__ void k0_swizzle(const float* __restrict__ Ua, uint4* __restrict__ UaSw) {
    int t = blockIdx.x * 256 + threadIdx.x;   // 0..131071
    int lane = t & 63;
    int nt = (t >> 6) & 7;
    int kc = (t >> 9) & 31;
    int nb = t >> 14;
    int n = nb * 128 + nt * 16 + (lane & 15);
    int k = kc * 32 + ((lane >> 4) & 3) * 8;
    const float4* src = (const float4*)(Ua + (size_t)n * H + k);
    UaSw[t] = pack8(src[0], src[1]);
}

// ---------------------------------------------------------------------------
// KA: keys fp32 [b*S+s][h] -> bf16 MFMA A-frag order:
// Abf[g], g = (stile*32 + kc)*64 + lane; stile = (b*S+s)/16
// row = stile*16 + (lane&15); col = kc*32 + ((lane>>4)&3)*8 + j
__global__ __launch_bounds__(256) void ka_swz(const float* __restrict__ keys,
                                              uint4* __restrict__ Abf) {
    size_t g = (size_t)blockIdx.x * 256 + threadIdx.x;   // 0..8388607
    int lane = (int)(g & 63);
    size_t u = g >> 6;
    int kc = (int)(u & 31);
    size_t stile = u >> 5;                                // 0..4095
    size_t row = stile * 16 + (lane & 15);
    int col = kc * 32 + ((lane >> 4) & 3) * 8;
    const float4* src = (const float4*)(keys + row * H + col);
    Abf[g] = pack8(src[0], src[1]);
}

// ---------------------------------------------------------------------------
// K1: qp[b][n] = sum_h query[b][h]*Wa_w[n][h] + Wa_b[n] + Ua_b[n]
__global__ __launch_bounds__(256) void k1_qproj(
    const float* __restrict__ q, const float* __restrict__ Wa,
    const float* __restrict__ Wab, const float* __restrict__ Uab,
    float* __restrict__ qp) {
    int b = blockIdx.y;
    int t = threadIdx.x;
    int n = blockIdx.x * 64 + (t >> 2);
    int quarter = t & 3;
    __shared__ float qs[H];
    for (int i = t; i < H; i += 256) qs[i] = q[b * H + i];
    __syncthreads();
    const float4* wr = (const float4*)(Wa + (size_t)n * H + quarter * 256);
    const float* qq = qs + quarter * 256;
    float acc = 0.f;
#pragma unroll 4
    for (int i = 0; i < 64; i++) {
        float4 w = wr[i];
        acc += qq[i * 4 + 0] * w.x + qq[i * 4 + 1] * w.y +
               qq[i * 4 + 2] * w.z + qq[i * 4 + 3] * w.w;
    }
    acc += __shfl_xor(acc, 1, 64);
    acc += __shfl_xor(acc, 2, 64);
    if (quarter == 0) qp[b * H + n] = acc + Wab[n] + Uab[n];
}

// ---------------------------------------------------------------------------
// K2v2: barrier-free streaming GEMM. Block = 128 rows x 128 n (one nb).
// 4 waves: wave wm owns 2 m-tiles (rows wm*32..+32) x full N=128 (8 n-tiles).
// Per kc: 10 coalesced 16B frag loads (prefetched 1 kc ahead) + 16 MFMA.
// No LDS, no __syncthreads in the K-loop. Per-nb partials stored directly.
__global__ __launch_bounds__(256, 2) void k2_scores2(
    const uint4* __restrict__ Abf, const uint4* __restrict__ UaSw,
    const float* __restrict__ qp, const float* __restrict__ Vaw,
    float* __restrict__ sp) {
    const int tid = threadIdx.x;
    const int lane = tid & 63;
    const int wm = tid >> 6;
    const int lid = blockIdx.x;      // 0..4095
    const int c = lid & 7;           // XCD slot (round-robin by linear id)
    const int qq = lid >> 3;
    const int nb = qq & 7;           // nb cycles fastest within an XCD
    const int mb = (qq >> 3) * 8 + c;
    const int b = mb >> 4;
    const int s0 = (mb & 15) << 7;

    const int stile0 = mb * 8 + wm * 2;
    const uint4* pa = Abf + (size_t)stile0 * 2048 + lane;   // kc stride 64, mt stride 2048
    const uint4* pb = UaSw + (size_t)nb * 16384 + lane;     // kc stride 512, nt stride 64

    f32x4 acc[2][8];
#pragma unroll
    for (int mt = 0; mt < 2; mt++)
#pragma unroll
        for (int nt = 0; nt < 8; nt++) acc[mt][nt] = (f32x4){0.f, 0.f, 0.f, 0.f};

    U4 ca[2], cb[8], na[2], nbf[8];
    ca[0].u = pa[0];
    ca[1].u = pa[2048];
#pragma unroll
    for (int nt = 0; nt < 8; nt++) cb[nt].u = pb[nt * 64];

    for (int kc = 0; kc < 32; kc++) {
        if (kc < 31) {
            na[0].u = pa[(kc + 1) * 64];
            na[1].u = pa[(kc + 1) * 64 + 2048];
#pragma unroll
            for (int nt = 0; nt < 8; nt++) nbf[nt].u = pb[(kc + 1) * 512 + nt * 64];
        }
#pragma unroll
        for (int nt = 0; nt < 8; nt++)
#pragma unroll
            for (int mt = 0; mt < 2; mt++)
                acc[mt][nt] = __builtin_amdgcn_mfma_f32_16x16x32_bf16(
                    ca[mt].b, cb[nt].b, acc[mt][nt], 0, 0, 0);
        if (kc < 31) {
            ca[0] = na[0]; ca[1] = na[1];
#pragma unroll
            for (int nt = 0; nt < 8; nt++) cb[nt] = nbf[nt];
        }
    }

    // epilogue: tanh, dot Va, shfl-reduce over col(16), direct store (disjoint rows)
    const int col = lane & 15, qd = lane >> 4;
    float qv[8], vv[8];
#pragma unroll
    for (int nt = 0; nt < 8; nt++) {
        int n = nb * 128 + nt * 16 + col;
        qv[nt] = qp[b * H + n];
        vv[nt] = Vaw[n];
    }
#pragma unroll
    for (int mt = 0; mt < 2; mt++) {
        float rs[4] = {0.f, 0.f, 0.f, 0.f};
#pragma unroll
        for (int nt = 0; nt < 8; nt++)
#pragma unroll
            for (int r = 0; r < 4; r++)
                rs[r] += ftanh(acc[mt][nt][r] + qv[nt]) * vv[nt];
#pragma unroll
        for (int r = 0; r < 4; r++) {
            float v = rs[r];
            v += __shfl_xor(v, 1, 64);
            v += __shfl_xor(v, 2, 64);
            v += __shfl_xor(v, 4, 64);
            v += __shfl_xor(v, 8, 64);
            if (col == 0)
                sp[(size_t)nb * B * S + b * S + s0 + wm * 32 + mt * 16 + qd * 4 + r] = v;
        }
    }
}

// ---------------------------------------------------------------------------
// K4v2: fused partial-sum + softmax + weights-write + context from bf16 keys.
// grid (8,32): block (kcg,b); wave wv handles kc=kcg*4+wv. Each (b,kc,q,j)
// owns unique context cols -> plain stores, no pre-zero needed.
__global__ __launch_bounds__(256) void k4_ctx2(const uint4* __restrict__ Abf,
                                               const float* __restrict__ sp,
                                               float* __restrict__ out) {
    int kcg = blockIdx.x, b = blockIdx.y;
    int t = threadIdx.x;
    __shared__ float red[256];
    __shared__ float wl[S];   // 8 KB

    float v[8];
#pragma unroll
    for (int i = 0; i < 8; i++) {
        int s = i * 256 + t;
        float sum = 0.f;
#pragma unroll
        for (int nb = 0; nb < 8; nb++) sum += sp[(size_t)nb * B * S + b * S + s];
        v[i] = sum;
    }
    float lm = -1e30f;
#pragma unroll
    for (int i = 0; i < 8; i++) lm = fmaxf(lm, v[i]);
    red[t] = lm;
    __syncthreads();
    for (int s = 128; s > 0; s >>= 1) {
        if (t < s) red[t] = fmaxf(red[t], red[t + s]);
        __syncthreads();
    }
    float m = red[0];
    __syncthreads();
    float ls = 0.f;
#pragma unroll
    for (int i = 0; i < 8; i++) ls += __expf(v[i] - m);
    red[t] = ls;
    __syncthreads();
    for (int s = 128; s > 0; s >>= 1) {
        if (t < s) red[t] += red[t + s];
        __syncthreads();
    }
    float inv = 1.f / red[0];
#pragma unroll
    for (int i = 0; i < 8; i++) {
        int s = i * 256 + t;
        float w = __expf(v[i] - m) * inv;
        wl[s] = w;
        if (kcg == 0) out[B * H + b * S + s] = w;
    }
    __syncthreads();

    const int wv = t >> 6, lane = t & 63, qd = lane >> 4, colr = lane & 15;
    const int kc = kcg * 4 + wv;
    float a8[8] = {0.f, 0.f, 0.f, 0.f, 0.f, 0.f, 0.f, 0.f};
    const uint4* base = Abf + ((size_t)(b * 128) * 32 + kc) * 64 + lane;
    for (int st = 0; st < 128; st++) {
        uint4 f = base[(size_t)st * 2048];
        float w = wl[st * 16 + colr];
        a8[0] += w * __uint_as_float(f.x << 16);
        a8[1] += w * __uint_as_float(f.x & 0xffff0000u);
        a8[2] += w * __uint_as_float(f.y << 16);
        a8[3] += w * __uint_as_float(f.y & 0xffff0000u);
        a8[4] += w * __uint_as_float(f.z << 16);
        a8[5] += w * __uint_as_float(f.z & 0xffff0000u);
        a8[6] += w * __uint_as_float(f.w << 16);
        a8[7] += w * __uint_as_float(f.w & 0xffff0000u);
    }
#pragma unroll
    for (int j = 0; j < 8; j++) {
        float vj = a8[j];
        vj += __shfl_xor(vj, 1, 64);
        vj += __shfl_xor(vj, 2, 64);
        vj += __shfl_xor(vj, 4, 64);
        vj += __shfl_xor(vj, 8, 64);
        a8[j] = vj;
    }
    if (colr == 0) {
        int colbase = kc * 32 + qd * 8;
#pragma unroll
        for (int j = 0; j < 8; j++) out[b * H + colbase + j] = a8[j];
    }
}

// ===========================================================================
// Fallback path (ws too small): round-4 kernels
// ===========================================================================
__global__ __launch_bounds__(256, 3) void k2_scores_fb(
    const float* __restrict__ keys, const uint4* __restrict__ UaSw,
    const float* __restrict__ qp, const float* __restrict__ Vaw,
    float* __restrict__ sp) {
    __shared__ uint4 As[2][512];
    __shared__ uint4 Bs[2][512];
    __shared__ float part[2][128];
    const int tid = threadIdx.x;
    const int lane = tid & 63;
    const int wave = tid >> 6;
    const int wm = wave >> 1, wn = wave & 1;
    const int lid = blockIdx.x;
    const int c = lid & 7;
    const int qq = lid >> 3;
    const int nb = qq & 7;
    const int mb = (qq >> 3) * 8 + c;
    const int b = mb >> 4;
    const int s0 = (mb & 15) << 7;
    const int el = tid & 63;
    const int srow0 = s0 + (tid >> 6) * 16 + (el & 15);
    const int srow1 = srow0 + 64;
    const int kofs = ((el >> 4) & 3) * 8;
    const float4* ka0 = (const float4*)(keys + ((size_t)b * S + srow0) * H + kofs);
    const float4* ka1 = (const float4*)(keys + ((size_t)b * S + srow1) * H + kofs);
    const uint4* srcB = UaSw + (size_t)nb * 32 * 512;
    f32x4 acc[4][4];
#pragma unroll
    for (int mt = 0; mt < 4; mt++)
#pragma unroll
        for (int nt = 0; nt < 4; nt++) acc[mt][nt] = (f32x4){0.f, 0.f, 0.f, 0.f};
    float4 x0 = ka0[0], y0 = ka0[1], x1 = ka1[0], y1 = ka1[1];
    async_copy16(srcB + tid,       &Bs[0][tid]);
    async_copy16(srcB + tid + 256, &Bs[0][tid + 256]);
    As[0][tid]       = pack8(x0, y0);
    As[0][tid + 256] = pack8(x1, y1);
    x0 = ka0[8]; y0 = ka0[9]; x1 = ka1[8]; y1 = ka1[9];
    __syncthreads();
    for (int kc = 0; kc < 32; kc++) {
        const int cur = kc & 1, nxt = cur ^ 1;
        if (kc < 31) {
            async_copy16(srcB + (size_t)(kc + 1) * 512 + tid,       &Bs[nxt][tid]);
            async_copy16(srcB + (size_t)(kc + 1) * 512 + tid + 256, &Bs[nxt][tid + 256]);
            As[nxt][tid]       = pack8(x0, y0);
            As[nxt][tid + 256] = pack8(x1, y1);
            if (kc < 30) {
                x0 = ka0[(kc + 2) * 8]; y0 = ka0[(kc + 2) * 8 + 1];
                x1 = ka1[(kc + 2) * 8]; y1 = ka1[(kc + 2) * 8 + 1];
            }
        }
        U4 af[4], bf[4];
#pragma unroll
        for (int mt = 0; mt < 4; mt++) af[mt].u = As[cur][(wm * 4 + mt) * 64 + lane];
#pragma unroll
        for (int nt = 0; nt < 4; nt++) bf[nt].u = Bs[cur][(wn * 4 + nt) * 64 + lane];
#pragma unroll
        for (int mt = 0; mt < 4; mt++)
#pragma unroll
            for (int nt = 0; nt < 4; nt++)
                acc[mt][nt] = __builtin_amdgcn_mfma_f32_16x16x32_bf16(
                    af[mt].b, bf[nt].b, acc[mt][nt], 0, 0, 0);
        __syncthreads();
    }
    const int col = lane & 15, qd = lane >> 4;
    float qv[4], vv[4];
#pragma unroll
    for (int nt = 0; nt < 4; nt++) {
        int n = nb * 128 + (wn * 4 + nt) * 16 + col;
        qv[nt] = qp[b * H + n];
        vv[nt] = Vaw[n];
    }
#pragma unroll
    for (int mt = 0; mt < 4; mt++) {
        float rs[4] = {0.f, 0.f, 0.f, 0.f};
#pragma unroll
        for (int nt = 0; nt < 4; nt++)
#pragma unroll
            for (int r = 0; r < 4; r++)
                rs[r] += ftanh(acc[mt][nt][r] + qv[nt]) * vv[nt];
#pragma unroll
        for (int r = 0; r < 4; r++) {
            float v = rs[r];
            v += __shfl_xor(v, 1, 64);
            v += __shfl_xor(v, 2, 64);
            v += __shfl_xor(v, 4, 64);
            v += __shfl_xor(v, 8, 64);
            if (col == 0) part[wn][wm * 64 + mt * 16 + qd * 4 + r] = v;
        }
    }
    __syncthreads();
    if (tid < 128)
        sp[(size_t)nb * B * S + b * S + s0 + tid] = part[0][tid] + part[1][tid];
}

__global__ __launch_bounds__(256) void k4_ctx_fb(const float* __restrict__ keys,
                                                 const float* __restrict__ sp,
                                                 float* __restrict__ out) {
    int sc = blockIdx.x, b = blockIdx.y;
    int t = threadIdx.x;
    __shared__ float red[256];
    __shared__ float wl[64];
    float v[8];
#pragma unroll
    for (int i = 0; i < 8; i++) {
        int s = i * 256 + t;
        float sum = 0.f;
#pragma unroll
        for (int nb = 0; nb < 8; nb++) sum += sp[(size_t)nb * B * S + b * S + s];
        v[i] = sum;
    }
    float lm = -1e30f;
#pragma unroll
    for (int i = 0; i < 8; i++) lm = fmaxf(lm, v[i]);
    red[t] = lm;
    __syncthreads();
    for (int s = 128; s > 0; s >>= 1) {
        if (t < s) red[t] = fmaxf(red[t], red[t + s]);
        __syncthreads();
    }
    float m = red[0];
    __syncthreads();
    float ls = 0.f;
#pragma unroll
    for (int i = 0; i < 8; i++) ls += __expf(v[i] - m);
    red[t] = ls;
    __syncthreads();
    for (int s = 128; s > 0; s >>= 1) {
        if (t < s) red[t] += red[t + s];
        __syncthreads();
    }
    float inv = 1.f / red[0];
    if (t < 64) {
        int s = sc * 64 + t;
        float sum = 0.f;
#pragma unroll
        for (int nb = 0; nb < 8; nb++) sum += sp[(size_t)nb * B * S + b * S + s];
        float w = __expf(sum - m) * inv;
        wl[t] = w;
        out[B * H + b * S + s] = w;
    }
    __syncthreads();
    const float4* kp = (const float4*)(keys + ((size_t)b * S + sc * 64) * H) + t;
    float4 acc = {0.f, 0.f, 0.f, 0.f};
#pragma unroll 8
    for (int s = 0; s < 64; s++) {
        float4 kv = kp[(size_t)s * 256];
        float w = wl[s];
        acc.x += w * kv.x; acc.y += w * kv.y;
        acc.z += w * kv.z; acc.w += w * kv.w;
    }
    float* dst = out + b * H + t * 4;
    atomicAdd(dst + 0, acc.x);
    atomicAdd(dst + 1, acc.y);
    atomicAdd(dst + 2, acc.z);
    atomicAdd(dst + 3, acc.w);
}

// ---------------------------------------------------------------------------
extern "C" void kernel_launch(void* const* d_in, const int* in_sizes, int n_in,
                              void* d_out, int out_size, void* d_ws, size_t ws_size,
                              hipStream_t stream) {
    const float* query = (const float*)d_in[0];
    const float* keys  = (const float*)d_in[1];
    const float* Wa_w  = (const float*)d_in[2];
    const float* Wa_b  = (const float*)d_in[3];
    const float* Ua_w  = (const float*)d_in[4];
    const float* Ua_b  = (const float*)d_in[5];
    const float* Va_w  = (const float*)d_in[6];
    float* out = (float*)d_out;

    // ws: [0,2MB) UaSw; [2MB,+128KB) qp; [2MB+128KB,+2MB) sp; [8MB,+128MB) Abf
    uint4* UaSw = (uint4*)d_ws;
    float* qp = (float*)((char*)d_ws + (2u << 20));
    float* sp = (float*)((char*)d_ws + (2u << 20) + (128u << 10));
    uint4* Abf = (uint4*)((char*)d_ws + (8u << 20));
    const size_t NEED = (size_t)(8u << 20) + ((size_t)128u << 20);

    if (ws_size >= NEED) {
        ka_swz<<<32768, 256, 0, stream>>>(keys, Abf);
        k0_swizzle<<<512, 256, 0, stream>>>(Ua_w, UaSw);
        k1_qproj<<<dim3(16, B), 256, 0, stream>>>(query, Wa_w, Wa_b, Ua_b, qp);
        k2_scores2<<<4096, 256, 0, stream>>>(Abf, UaSw, qp, Va_w, sp);
        k4_ctx2<<<dim3(8, B), 256, 0, stream>>>(Abf, sp, out);
    } else {
        hipMemsetAsync(d_out, 0, B * H * sizeof(float), stream);
        k0_swizzle<<<512, 256, 0, stream>>>(Ua_w, UaSw);
        k1_qproj<<<dim3(16, B), 256, 0, stream>>>(query, Wa_w, Wa_b, Ua_b, qp);
        k2_scores_fb<<<4096, 256, 0, stream>>>(keys, UaSw, qp, Va_w, sp);
        k4_ctx_fb<<<dim3(32, B), 256, 0, stream>>>(keys, sp, out);
    }
}